// Round 5
// baseline (695.480 us; speedup 1.0000x reference)
//
#include <hip/hip_runtime.h>
#include <math.h>

// Problem constants (match reference)
#define NB   64     // num_groups (B)
#define NG   32     // group_size (G)
#define ND   2000   // output dim D
#define NM   16     // m_samples
#define NE   16     // noise dim
#define NDIN 256
#define NK   272    // DIN + E

// ---------------------------------------------------------------------------
// Round-5 k_ipf design (from round-4 per-kernel profile):
//   k_ipf was 511us = 96% of GPU time, on only 64 blocks (25% of CUs), with
//   +41MB scratch WRITE from the spilled epilogue (VGPR=64 again).
//   Fix 1: 4 blocks per b (grid 256 = #CUs, co-resident by construction).
//     Each block owns 512 d-columns -> ALL columns LDS-resident (64KB),
//     no L2 streaming in the loop.  Cross-block row reduction per iter via
//     device-scope atomics: publish 4 per-wave partials (16 per b total,
//     same wave->d mapping as the old 16-wave kernel => bit-identical FP
//     combine order), counter release-add, spin, ordered 16-term sum.
//     Partner blocks {b,b+64,b+128,b+192} share an XCD (round-robin map).
//   Fix 2: epilogue frac/yv in a dedicated LDS region (256B/thread,
//     bank-rotated (g+tt)&31) -> no register arrays -> nothing to spill.
// ---------------------------------------------------------------------------
#define DPB  512                      // d-columns per ipf block
#define EPI  65536                    // byte offset of epilogue region
#define SMEM_IPF (EPI + 256 * 256)    // 64KB y0 cols + 64KB epi = 131072

__device__ __forceinline__ float clampf(float v, float lo, float hi) {
    return fminf(fmaxf(v, lo), hi);
}

__device__ __forceinline__ float softplusf(float v) {
    return (v > 20.f) ? v : log1pf(expf(v));
}

// Broadcast lane's value as a WAVE-UNIFORM (SGPR) value.
__device__ __forceinline__ float readlane_f(float v, int lane) {
    return __int_as_float(__builtin_amdgcn_readlane(__float_as_int(v), lane));
}

// Fully-packed butterfly: reduce v[0..31] (per-g partials) across 64 lanes in
// 32 shuffles.  Returns the wave total for g = (lane>>1)&31 (dup on pairs).
__device__ __forceinline__ float wave_sum32(float v[NG], int lane) {
    {   const bool hi = (lane & 32) != 0;
        #pragma unroll
        for (int k = 0; k < 16; ++k) {
            float s = hi ? v[k] : v[k + 16];
            float r = __shfl_xor(s, 32);
            v[k] = (hi ? v[k + 16] : v[k]) + r;
        }
    }
    {   const bool hi = (lane & 16) != 0;
        #pragma unroll
        for (int k = 0; k < 8; ++k) {
            float s = hi ? v[k] : v[k + 8];
            float r = __shfl_xor(s, 16);
            v[k] = (hi ? v[k + 8] : v[k]) + r;
        }
    }
    {   const bool hi = (lane & 8) != 0;
        #pragma unroll
        for (int k = 0; k < 4; ++k) {
            float s = hi ? v[k] : v[k + 4];
            float r = __shfl_xor(s, 8);
            v[k] = (hi ? v[k + 4] : v[k]) + r;
        }
    }
    {   const bool hi = (lane & 4) != 0;
        #pragma unroll
        for (int k = 0; k < 2; ++k) {
            float s = hi ? v[k] : v[k + 2];
            float r = __shfl_xor(s, 4);
            v[k] = (hi ? v[k + 2] : v[k]) + r;
        }
    }
    {   const bool hi = (lane & 2) != 0;
        float s = hi ? v[0] : v[1];
        float r = __shfl_xor(s, 2);
        v[0] = (hi ? v[1] : v[0]) + r;
    }
    v[0] += __shfl_xor(v[0], 1);
    return v[0];
}

// All 4 waves' partial stores are drained by __syncthreads (vmcnt 0), then
// t0 release-adds the arrive counter and spins until all 4 partner blocks
// arrived.  Acquire + barrier orders the partial loads after.
__device__ __forceinline__ void arrive_and_wait(int* cnt_b, int tt, int target) {
    __syncthreads();
    if (tt == 0) {
        __hip_atomic_fetch_add(cnt_b, 1, __ATOMIC_RELEASE, __HIP_MEMORY_SCOPE_AGENT);
        while (__hip_atomic_load(cnt_b, __ATOMIC_ACQUIRE, __HIP_MEMORY_SCOPE_AGENT) < target)
            __builtin_amdgcn_s_sleep(1);
    }
    __syncthreads();
}

extern "C" __global__ __launch_bounds__(256)
void k_ipf(const float* __restrict__ xpT, const int* __restrict__ tsum,
           float* __restrict__ out, float* __restrict__ partials,
           int* __restrict__ cnt) {
    extern __shared__ char smem[];
    const int bid = blockIdx.x;
    const int b   = bid & 63;          // partners {b,b+64,b+128,b+192}: same XCD
    const int sub = bid >> 6;          // 0..3
    const int tt  = threadIdx.x;       // 0..255
    const int lane = tt & 63, w = tt >> 6;
    const int wglob = sub * 4 + w;     // == old 16-wave id (bit-exact combine)
    const int dloc = tt * 2;
    const int d0 = sub * DPB + dloc;   // global d of column pair
    const bool valid = (d0 < ND);
    const int g_own = (lane >> 1) & 31;
    const int rot = tt & 7;
    char* base0 = smem + (size_t)dloc * 128;
    char* base1 = base0 + 128;
    float* epf = (float*)(smem + EPI + (size_t)tt * 256);        // frac[32]
    int*   epy = (int*)(smem + EPI + (size_t)tt * 256 + 128);    // yv[32]

    int* cnt_b = cnt + b;
    float* pb = partials + (size_t)b * (2 * 16 * 32);  // [buf][w'][g]

    float Cc[2] = {0.f, 0.f};
    if (valid) {
        const int2 ci = *(const int2*)(tsum + (size_t)b * ND + d0);
        Cc[0] = (float)ci.x; Cc[1] = (float)ci.y;
    }
    float Ac[2] = {1.f, 1.f};
    float Bown = 1.f;                  // lane-pair's B[g_own]
    float Rown;                        // lane-pair's R[g_own]

    // prologue: load columns (relu of softplus = identity), stash in LDS
    // (zeros for invalid threads so all later passes are branch-free),
    // compute row anchors R via 16-partial ordered combine.
    {
        float v[NG];
        const float4* gp = (const float4*)(xpT + ((size_t)b * ND + d0) * NG);
        if (valid) {
            #pragma unroll
            for (int k = 0; k < 8; ++k) {
                const float4 a = gp[k];
                const float4 c = gp[8 + k];
                v[4*k+0] = a.x + c.x;
                v[4*k+1] = a.y + c.y;
                v[4*k+2] = a.z + c.z;
                v[4*k+3] = a.w + c.w;
                const int ro = 16 * ((k + rot) & 7);
                *(float4*)(base0 + ro) = a;
                *(float4*)(base1 + ro) = c;
            }
        } else {
            const float4 zz = make_float4(0.f, 0.f, 0.f, 0.f);
            #pragma unroll
            for (int k = 0; k < 8; ++k) {
                const int ro = 16 * ((k + rot) & 7);
                *(float4*)(base0 + ro) = zz;
                *(float4*)(base1 + ro) = zz;
            }
            #pragma unroll
            for (int g = 0; g < NG; ++g) v[g] = 0.f;
        }
        const float tot = wave_sum32(v, lane);
        if (!(lane & 1))
            __hip_atomic_store(&pb[wglob * 32 + g_own], tot,
                               __ATOMIC_RELAXED, __HIP_MEMORY_SCOPE_AGENT);
        arrive_and_wait(cnt_b, tt, 4);
        float s = 0.f;
        #pragma unroll
        for (int w2 = 0; w2 < 16; ++w2)
            s += __hip_atomic_load(&pb[w2 * 32 + g_own],
                                   __ATOMIC_RELAXED, __HIP_MEMORY_SCOPE_AGENT);
        Rown = s;
    }

    // 60 IPF iterations; double-buffered partials, one global sync each.
    for (int q = 1; q <= 60; ++q) {
        // ---- column pass: s(d) = sum_g y0[g,d] * B[g] (thread-local) ----
        float s0 = 0.f, s1 = 0.f;
        #pragma unroll
        for (int k = 0; k < 8; ++k) {
            const int ro = 16 * ((k + rot) & 7);
            const float4 a = *(const float4*)(base0 + ro);
            const float4 c = *(const float4*)(base1 + ro);
            float bg;
            bg = readlane_f(Bown, 8*k+0); s0 += a.x * bg; s1 += c.x * bg;
            bg = readlane_f(Bown, 8*k+2); s0 += a.y * bg; s1 += c.y * bg;
            bg = readlane_f(Bown, 8*k+4); s0 += a.z * bg; s1 += c.z * bg;
            bg = readlane_f(Bown, 8*k+6); s0 += a.w * bg; s1 += c.w * bg;
        }
        Ac[0] *= clampf(Cc[0] / fmaxf(Ac[0] * s0, 1e-12f), 0.75f, 1.25f);
        Ac[1] *= clampf(Cc[1] / fmaxf(Ac[1] * s1, 1e-12f), 0.75f, 1.25f);

        asm volatile("" ::: "memory");   // keep passes separate (reg pressure)

        // ---- row pass: v[g] = y0[g,d0]*A[d0] + y0[g,d1]*A[d1] ----
        float v[NG];
        #pragma unroll
        for (int k = 0; k < 8; ++k) {
            const int ro = 16 * ((k + rot) & 7);
            const float4 a = *(const float4*)(base0 + ro);
            const float4 c = *(const float4*)(base1 + ro);
            v[4*k+0] = a.x * Ac[0] + c.x * Ac[1];
            v[4*k+1] = a.y * Ac[0] + c.y * Ac[1];
            v[4*k+2] = a.z * Ac[0] + c.z * Ac[1];
            v[4*k+3] = a.w * Ac[0] + c.w * Ac[1];
        }
        const float tot = wave_sum32(v, lane);
        const int buf = q & 1;
        if (!(lane & 1))
            __hip_atomic_store(&pb[buf * 512 + wglob * 32 + g_own], tot,
                               __ATOMIC_RELAXED, __HIP_MEMORY_SCOPE_AGENT);
        arrive_and_wait(cnt_b, tt, 4 * (q + 1));
        float s = 0.f;
        #pragma unroll
        for (int w2 = 0; w2 < 16; ++w2)
            s += __hip_atomic_load(&pb[buf * 512 + w2 * 32 + g_own],
                                   __ATOMIC_RELAXED, __HIP_MEMORY_SCOPE_AGENT);
        Bown *= clampf(Rown / fmaxf(Bown * s, 1e-12f), 0.75f, 1.25f);
    }

    // ---- epilogue: final scale + exact integerization ----
    // frac/yv live in LDS (bank-rotated (g+tt)&31): nothing for the
    // allocator to spill (round-4's +41MB scratch disaster).
    if (!valid) return;

    #pragma unroll
    for (int j = 0; j < 2; ++j) {
        const char* basej = j ? base1 : base0;
        // pass 1: z = y0 * A * B, accumulate s (same order as rounds 0-4)
        float s = 0.f;
        #pragma unroll
        for (int k = 0; k < 8; ++k) {
            const int ro = 16 * ((k + rot) & 7);
            const float4 a = *(const float4*)(basej + ro);
            float z;
            z = a.x * Ac[j] * readlane_f(Bown, 8*k+0); s += z; epf[(4*k+0+tt)&31] = z;
            z = a.y * Ac[j] * readlane_f(Bown, 8*k+2); s += z; epf[(4*k+1+tt)&31] = z;
            z = a.z * Ac[j] * readlane_f(Bown, 8*k+4); s += z; epf[(4*k+2+tt)&31] = z;
            z = a.w * Ac[j] * readlane_f(Bown, 8*k+6); s += z; epf[(4*k+3+tt)&31] = z;
        }
        const float F = Cc[j] / fmaxf(s, 1e-12f);
        // pass 2: floor/frac/yv, isum (ascending g, as before)
        int isum = 0;
        #pragma unroll
        for (int g = 0; g < NG; ++g) {
            const float y = epf[(g+tt)&31] * F;
            const float fl = floorf(y);
            const int yi = (int)fl;
            epf[(g+tt)&31] = y - fl;
            epy[(g+tt)&31] = yi;
            isum += yi;
        }
        const int Ci = (int)Cc[j];
        const int need = Ci - isum;
        const int pos = max(need, 0);
        const int qq = pos >> 5;
        const int r = pos & 31;
        if (qq > 0) {
            #pragma unroll
            for (int g = 0; g < NG; ++g) epy[(g+tt)&31] += qq;
        }
        #pragma unroll
        for (int g = 0; g < NG; ++g) {       // stable DESCENDING rank on frac
            const float fg = epf[(g+tt)&31];
            int rank = 0;
            #pragma unroll
            for (int h = 0; h < NG; ++h) {
                if (h == g) continue;
                const float fh = epf[(h+tt)&31];
                rank += (h < g) ? (fh >= fg ? 1 : 0) : (fh > fg ? 1 : 0);
            }
            if (rank < r) epy[(g+tt)&31] += 1;
        }
        // negative residual: one-shot ascending rank among yv>0 (== reference)
        int neg = max(-need, 0);
        neg = min(neg, isum);
        if (__builtin_expect(neg > 0, 0)) {
            const int q2 = neg >> 5;
            int removed = 0;
            #pragma unroll
            for (int g = 0; g < NG; ++g) {
                const int yb = epy[(g+tt)&31];
                const int yn = max(yb - q2, 0);
                removed += yb - yn;
                epy[(g+tt)&31] = yn;
            }
            const int r2 = neg - removed;
            if (r2 > 0) {
                const float INF = __builtin_inff();
                #pragma unroll
                for (int g = 0; g < NG; ++g) {
                    const float fg = (epy[(g+tt)&31] > 0) ? epf[(g+tt)&31] : INF;
                    int rank = 0;
                    #pragma unroll
                    for (int h = 0; h < NG; ++h) {
                        if (h == g) continue;
                        const float fh = (epy[(h+tt)&31] > 0) ? epf[(h+tt)&31] : INF;
                        rank += (h < g) ? (fh <= fg ? 1 : 0) : (fh < fg ? 1 : 0);
                    }
                    if (rank < r2) {
                        const int yb = epy[(g+tt)&31];
                        epy[(g+tt)&31] = max(yb - 1, 0);
                    }
                }
            }
        }
        #pragma unroll
        for (int g = 0; g < NG; ++g)
            out[1 + (size_t)(b * NG + g) * ND + d0 + j] = (float)epy[(g+tt)&31];
    }
}

// ---------------------------------------------------------------------------
// K_LOSS: 256 blocks x 1024 thr = two 512-halves, 36KB STATIC LDS
// (round-2 verbatim structure).
// ---------------------------------------------------------------------------
extern "C" __global__ __launch_bounds__(1024)
void k_loss(const float* __restrict__ x, const float* __restrict__ nl,
            const float* __restrict__ tgt, const float* __restrict__ W,
            const float* __restrict__ bias, float* __restrict__ res2) {
    __shared__ float smem[9080];               // 36.3 KB
    const int bid = blockIdx.x;                // 0..255
    const int b = bid >> 2;                    // 0..63
    const int t = threadIdx.x;
    const int cx = ((bid & 3) << 1) | (t >> 9);// 0..7 (half = t>>9)
    const int tt = t & 511;
    const int half = cx & 1;

    float* xsl = smem;                         // 256 (shared across halves)
    float* nsl = smem + 256;                   // 256 (shared across halves)
    float* tgl = smem + 512 + half * 4284;     // 252 per half
    float* pt  = tgl + 252;                    // 16 x 252 per half

    if (half == 0 && tt < 256) {               // == global t < 256
        const float* xb = x + (size_t)b * NG * NDIN;
        float s = 0.f;
        for (int g = 0; g < NG; ++g) s += xb[g * NDIN + tt];
        xsl[tt] = s;
        const float* nb = nl + (size_t)b * NG * (NM * NE);
        float s2 = 0.f;
        for (int g = 0; g < NG; ++g) s2 += nb[g * (NM * NE) + tt];
        nsl[tt] = s2;
    }

    int tm = 0, tn = 0;
    if (tt >= 16 && tt < 152) {
        int p = tt - 16;
        for (int m = 0; m < NM; ++m) {
            int c = NM - m;
            if (p < c) { tm = m; tn = m + p; break; }
            p -= c;
        }
    }
    __syncthreads();

    const int d = cx * 250 + tt;
    if (tt < 250) {
        tgl[tt] = tgt[b * ND + d];
        float xw = 0.f;
        #pragma unroll 8
        for (int k = 0; k < NDIN; ++k) xw += xsl[k] * W[(size_t)k * ND + d];
        float we[NE];
        #pragma unroll
        for (int e = 0; e < NE; ++e) we[e] = W[(size_t)(NDIN + e) * ND + d];
        const float base0 = xw + (float)NG * bias[d];
        #pragma unroll
        for (int m = 0; m < NM; ++m) {
            float pm = base0;
            #pragma unroll
            for (int e = 0; e < NE; ++e) pm += nsl[m * NE + e] * we[e];
            pt[m * 252 + tt] = pm;
        }
    }
    if (tt < 32) {                     // zero-pad cols 250,251
        pt[(tt >> 1) * 252 + 250 + (tt & 1)] = 0.f;
        if (tt < 2) tgl[250 + tt] = 0.f;
    }
    __syncthreads();

    float acc = 0.f;
    if (tt < 16) {
        const float4* pa  = (const float4*)&pt[tt * 252];
        const float4* tga = (const float4*)&tgl[0];
        for (int i = 0; i < 63; ++i) {
            float4 pv = pa[i], tv = tga[i];
            float e0 = pv.x - tv.x, e1 = pv.y - tv.y, e2 = pv.z - tv.z, e3 = pv.w - tv.w;
            acc += e0 * e0 + e1 * e1 + e2 * e2 + e3 * e3;
        }
    } else if (tt < 152) {
        const float4* pa = (const float4*)&pt[tm * 252];
        const float4* pb = (const float4*)&pt[tn * 252];
        for (int i = 0; i < 63; ++i) {
            float4 u = pa[i], v = pb[i];
            acc += u.x * v.x + u.y * v.y + u.z * v.z + u.w * v.w;
        }
    }
    if (tt < 152) res2[((size_t)b * 8 + cx) * 152 + tt] = acc;
}

// K2b: combine the 8 d-chunk partials per b and accumulate the loss.
extern "C" __global__ __launch_bounds__(64)
void k2b_combine(const float* __restrict__ res2, float* __restrict__ out) {
    const int b = blockIdx.x, t = threadIdx.x;
    __shared__ float res[152];
    for (int tau = t; tau < 152; tau += 64) {
        float s = 0.f;
        #pragma unroll
        for (int c = 0; c < 8; ++c) s += res2[((size_t)b * 8 + c) * 152 + tau];
        res[tau] = s;
    }
    __syncthreads();
    if (t == 0) {
        float conf = 0.f;
        for (int m = 0; m < NM; ++m) conf += sqrtf(res[m]);
        conf *= (1.f / NM);
        float pd = 0.f;
        for (int m = 0; m < NM; ++m) {
            const int offm = 16 + m * NM - m * (m - 1) / 2;
            const float sqm = res[offm];
            for (int n = m + 1; n < NM; ++n) {
                const int offn = 16 + n * NM - n * (n - 1) / 2;
                const float sqn = res[offn];
                const float inn = res[offm + (n - m)];
                pd += sqrtf(fmaxf(sqm + sqn - 2.f * inn, 1e-6f));
            }
        }
        pd = 2.f * pd / (float)(NM * (NM - 1));
        atomicAdd(out, (conf - 0.5f * pd) * (1.f / NB));
    }
}

// ---------------------------------------------------------------------------
// K3: x_pred = softplus(concat(x, noise_sample) @ W + bias), stored
// TRANSPOSED as xpT[b][d][g] (g contiguous) so the IPF path reads columns
// as contiguous 128 B runs.
// ---------------------------------------------------------------------------
extern "C" __global__ __launch_bounds__(256)
void k3_xpred(const float* __restrict__ x, const float* __restrict__ nsamp,
              const float* __restrict__ W, const float* __restrict__ bias,
              float* __restrict__ xpT) {
    const int dx = blockIdx.x;     // 0..1
    const int rb = blockIdx.y;     // 0..255
    const int t  = threadIdx.x;
    __shared__ float xr[8][NK];
    #pragma unroll
    for (int r = 0; r < 8; ++r) {
        const int row = rb * 8 + r;
        xr[r][t] = x[(size_t)row * NDIN + t];
        if (t < NE) xr[r][NDIN + t] = nsamp[row * NE + t];
    }
    __syncthreads();
    if (t >= 250) return;
    const int d = dx * 1000 + 4 * t;
    float acc[8][4];
    #pragma unroll
    for (int r = 0; r < 8; ++r) {
        acc[r][0] = 0.f; acc[r][1] = 0.f; acc[r][2] = 0.f; acc[r][3] = 0.f;
    }
    for (int k = 0; k < NK; k += 4) {
        float4 w[4];
        #pragma unroll
        for (int kk = 0; kk < 4; ++kk) w[kk] = *(const float4*)&W[(size_t)(k + kk) * ND + d];
        #pragma unroll
        for (int r = 0; r < 8; ++r) {
            const float4 xv = *(const float4*)&xr[r][k];
            acc[r][0] += xv.x * w[0].x + xv.y * w[1].x + xv.z * w[2].x + xv.w * w[3].x;
            acc[r][1] += xv.x * w[0].y + xv.y * w[1].y + xv.z * w[2].y + xv.w * w[3].y;
            acc[r][2] += xv.x * w[0].z + xv.y * w[1].z + xv.z * w[2].z + xv.w * w[3].z;
            acc[r][3] += xv.x * w[0].w + xv.y * w[1].w + xv.z * w[2].w + xv.w * w[3].w;
        }
    }
    const float4 bv = *(const float4*)&bias[d];
    const float bvv[4] = {bv.x, bv.y, bv.z, bv.w};
    const int b2 = rb >> 2;            // b = row/32
    const int g0 = (rb & 3) * 8;       // this thread-block's 8-g slice
    #pragma unroll
    for (int dd = 0; dd < 4; ++dd) {
        float* op = xpT + ((size_t)b2 * ND + (d + dd)) * NG + g0;
        float4 lo, hi;
        lo.x = softplusf(acc[0][dd] + bvv[dd]);
        lo.y = softplusf(acc[1][dd] + bvv[dd]);
        lo.z = softplusf(acc[2][dd] + bvv[dd]);
        lo.w = softplusf(acc[3][dd] + bvv[dd]);
        hi.x = softplusf(acc[4][dd] + bvv[dd]);
        hi.y = softplusf(acc[5][dd] + bvv[dd]);
        hi.z = softplusf(acc[6][dd] + bvv[dd]);
        hi.w = softplusf(acc[7][dd] + bvv[dd]);
        *(float4*)op       = lo;
        *(float4*)(op + 4) = hi;
    }
}

// ---------------------------------------------------------------------------
extern "C" void kernel_launch(void* const* d_in, const int* in_sizes, int n_in,
                              void* d_out, int out_size, void* d_ws, size_t ws_size,
                              hipStream_t stream) {
    const float* x     = (const float*)d_in[0];
    const float* tgt   = (const float*)d_in[1];
    const int*   tsum  = (const int*)d_in[2];
    const float* W     = (const float*)d_in[3];
    const float* bias  = (const float*)d_in[4];
    const float* nl    = (const float*)d_in[5];
    const float* nsamp = (const float*)d_in[6];
    float* out = (float*)d_out;
    float* xpT = (float*)d_ws;                         // 64*2000*32 floats

    (void)in_sizes; (void)n_in; (void)out_size; (void)ws_size;

    const size_t XPB = (size_t)2048 * 2000 * 4;        // 16,384,000 B
    // res2 region (311,296 B) is written only by k_loss AFTER k_ipf
    // completes (stream order), so k_ipf borrows it for partials+cnt:
    //   partials: float[64][2][16][32] = 262,144 B
    //   cnt:      int[64]              = 256 B
    float* res2     = (float*)((char*)d_ws + XPB);
    float* partials = res2;
    int*   cnt      = (int*)((char*)d_ws + XPB + 262144);

    static int s_attr_done = 0;
    if (!s_attr_done) {
        hipFuncSetAttribute(reinterpret_cast<const void*>(k_ipf),
                            hipFuncAttributeMaxDynamicSharedMemorySize,
                            SMEM_IPF);
        s_attr_done = 1;
    }

    hipMemsetAsync(d_out, 0, sizeof(float), stream);   // loss accumulator
    hipMemsetAsync(cnt, 0, 64 * sizeof(int), stream);  // arrive counters

    hipLaunchKernelGGL(k3_xpred, dim3(2, 256), dim3(256), 0, stream,
                       x, nsamp, W, bias, xpT);
    hipLaunchKernelGGL(k_ipf, dim3(256), dim3(256), SMEM_IPF, stream,
                       xpT, tsum, out, partials, cnt);
    hipLaunchKernelGGL(k_loss, dim3(256), dim3(1024), 0, stream,
                       x, nl, tgt, W, bias, res2);
    hipLaunchKernelGGL(k2b_combine, dim3(NB), dim3(64), 0, stream, res2, out);
}

// Round 6
// 414.689 us; speedup vs baseline: 1.6771x; 1.6771x over previous
//
#include <hip/hip_runtime.h>
#include <math.h>

// Problem constants (match reference)
#define NB   64     // num_groups (B)
#define NG   32     // group_size (G)
#define ND   2000   // output dim D
#define NM   16     // m_samples
#define NE   16     // noise dim
#define NDIN 256
#define NK   272    // DIN + E

// ---------------------------------------------------------------------------
// Round-6 design, from 5 rounds of profile evidence:
//  (1) register-resident y0 always spills (r0/r1/r2/r4: VGPR capped 64-84).
//  (2) per-iter cross-block atomics sync ~8us/iter (r5: 550us) - dead end.
//  (3) >256 blocks with 160KB dyn LDS serializes scheduling (r3).
//  (4) r4's L2 stream was 256B-stride per lane = 64 lines/dwordx4, 4x
//      over-fetch: THE stream cost.  Fix: lane-interleaved packed layout.
//  (5) butterfly cost ~ thread count: 512thr/4d halves it vs 1024thr/2d.
// Structure: ONE mega kernel, grid EXACTLY 256 x 512thr: 64 ipf blocks
// (1 per b, no cross-block sync, r0's FP order) + 192 loss blocks
// (grid-stride over 512 (b,chunk) pairs) -> loss fully hidden under ipf.
// ipf: 1024 cols in LDS (waves 0-3) + 976 cols streamed coalesced from
// streamP (waves 4-7).  Two-pass loop (no 64-float live set -> no spill).
// Integerization in separate k_epi (r5's proven LDS-scratch, spill-free),
// full 256-CU parallelism.  A/B finals parked in `out` rows that the SAME
// k_epi threads later overwrite (same-thread read-then-write + block
// barrier => race-free) -> ws stays at the proven 16.7MB footprint.
// ---------------------------------------------------------------------------
#define XPT_COLS 1024                       // cols 0..1023 in xpT
#define SP_STRIDE 7808                      // float4 per b in streamP
#define SMEM_MEGA (2048 + XPT_COLS * 128)   // 2KB wred + 128KB cols = 133120
#define SMEM_EPI  (128 + 256 * 256)         // 32 B[] + 256B/thread = 65664

__device__ __forceinline__ float clampf(float v, float lo, float hi) {
    return fminf(fmaxf(v, lo), hi);
}

__device__ __forceinline__ float softplusf(float v) {
    return (v > 20.f) ? v : log1pf(expf(v));
}

__device__ __forceinline__ float readlane_f(float v, int lane) {
    return __int_as_float(__builtin_amdgcn_readlane(__float_as_int(v), lane));
}

// streamP float4 index within one b (stride SP_STRIDE float4).
// Layout: [w''=tau>>6][cj][k][lane] with a tight 52-lane tail (tau>=192).
// For fixed (cj,k) the loads of a wave are lane-contiguous = coalesced.
__device__ __forceinline__ size_t sp_idx(int tau, int cj, int k) {
    return (tau < 192)
        ? ((size_t)((tau >> 6) * 2048 + cj * 512 + k * 64 + (tau & 63)))
        : ((size_t)(6144 + cj * 416 + k * 52 + (tau - 192)));
}

// Fully-packed butterfly: reduce v[0..31] (per-g partials) across 64 lanes in
// 32 shuffles.  Returns the wave total for g = (lane>>1)&31 (dup on pairs).
__device__ __forceinline__ float wave_sum32(float v[NG], int lane) {
    {   const bool hi = (lane & 32) != 0;
        #pragma unroll
        for (int k = 0; k < 16; ++k) {
            float s = hi ? v[k] : v[k + 16];
            float r = __shfl_xor(s, 32);
            v[k] = (hi ? v[k + 16] : v[k]) + r;
        }
    }
    {   const bool hi = (lane & 16) != 0;
        #pragma unroll
        for (int k = 0; k < 8; ++k) {
            float s = hi ? v[k] : v[k + 8];
            float r = __shfl_xor(s, 16);
            v[k] = (hi ? v[k + 8] : v[k]) + r;
        }
    }
    {   const bool hi = (lane & 8) != 0;
        #pragma unroll
        for (int k = 0; k < 4; ++k) {
            float s = hi ? v[k] : v[k + 4];
            float r = __shfl_xor(s, 8);
            v[k] = (hi ? v[k + 4] : v[k]) + r;
        }
    }
    {   const bool hi = (lane & 4) != 0;
        #pragma unroll
        for (int k = 0; k < 2; ++k) {
            float s = hi ? v[k] : v[k + 2];
            float r = __shfl_xor(s, 4);
            v[k] = (hi ? v[k + 2] : v[k]) + r;
        }
    }
    {   const bool hi = (lane & 2) != 0;
        float s = hi ? v[0] : v[1];
        float r = __shfl_xor(s, 2);
        v[0] = (hi ? v[1] : v[0]) + r;
    }
    v[0] += __shfl_xor(v[0], 1);
    return v[0];
}

// ---- IPF path: 512 thr, thread owns cols 4t..4t+3 (r0 FP structure) ------
__device__ __forceinline__ void ipf_path(
        const float* __restrict__ xpT, const float* __restrict__ spB,
        const int* __restrict__ tsum, float* __restrict__ out,
        char* smem, int b, int t) {
    const int lane = t & 63, w = t >> 6;       // 8 waves
    const int c0 = 4 * t;
    const bool valid = (t < 500);
    const bool lcls  = (t < 256);              // cols in LDS (waves 0-3)
    const int g_own = (lane >> 1) & 31;
    const int rot = t & 7;
    const int tau = t - 256;

    float* wred = (float*)smem;                // [2][8][32] dbuf
    char* cbase = smem + 2048 + (size_t)c0 * 128;   // 4 slots x 128B (t<256)
    const float4* gx = (const float4*)(xpT + ((size_t)b * XPT_COLS + c0) * NG);
    const float4* gs = (const float4*)(spB + (size_t)b * SP_STRIDE * 4);

    float Cc[4] = {0.f, 0.f, 0.f, 0.f};
    if (valid) {
        const int4 ci = *(const int4*)(tsum + (size_t)b * ND + c0);
        Cc[0] = (float)ci.x; Cc[1] = (float)ci.y;
        Cc[2] = (float)ci.z; Cc[3] = (float)ci.w;
    }
    float Ac[4] = {1.f, 1.f, 1.f, 1.f};
    float Bown = 1.f, Rown;

    // prologue: load 4 cols, stash LDS-class, row anchors R
    {
        float v[NG];
        if (lcls) {
            #pragma unroll
            for (int k = 0; k < 8; ++k) {
                const float4 a = gx[k], e = gx[8 + k], f = gx[16 + k], h = gx[24 + k];
                const int ro = 16 * ((k + rot) & 7);
                *(float4*)(cbase + ro)       = a;
                *(float4*)(cbase + 128 + ro) = e;
                *(float4*)(cbase + 256 + ro) = f;
                *(float4*)(cbase + 384 + ro) = h;
                v[4*k+0] = ((a.x + e.x) + f.x) + h.x;
                v[4*k+1] = ((a.y + e.y) + f.y) + h.y;
                v[4*k+2] = ((a.z + e.z) + f.z) + h.z;
                v[4*k+3] = ((a.w + e.w) + f.w) + h.w;
            }
        } else if (valid) {
            #pragma unroll
            for (int k = 0; k < 8; ++k) {
                const float4 a = gs[sp_idx(tau, 0, k)];
                const float4 e = gs[sp_idx(tau, 1, k)];
                const float4 f = gs[sp_idx(tau, 2, k)];
                const float4 h = gs[sp_idx(tau, 3, k)];
                v[4*k+0] = ((a.x + e.x) + f.x) + h.x;
                v[4*k+1] = ((a.y + e.y) + f.y) + h.y;
                v[4*k+2] = ((a.z + e.z) + f.z) + h.z;
                v[4*k+3] = ((a.w + e.w) + f.w) + h.w;
            }
        } else {
            #pragma unroll
            for (int g = 0; g < NG; ++g) v[g] = 0.f;
        }
        const float tot = wave_sum32(v, lane);
        if (!(lane & 1)) wred[w * NG + g_own] = tot;
        __syncthreads();
        float s = 0.f;
        #pragma unroll
        for (int w2 = 0; w2 < 8; ++w2) s += wred[w2 * NG + g_own];
        Rown = s;
    }

    // 60 IPF iterations, one barrier each (dbuf wred), NO cross-block sync
    for (int q = 1; q <= 60; ++q) {
        float s0 = 0.f, s1 = 0.f, s2 = 0.f, s3 = 0.f;
        if (lcls) {
            #pragma unroll
            for (int k = 0; k < 8; ++k) {
                const int ro = 16 * ((k + rot) & 7);
                const float4 a = *(const float4*)(cbase + ro);
                const float4 e = *(const float4*)(cbase + 128 + ro);
                const float4 f = *(const float4*)(cbase + 256 + ro);
                const float4 h = *(const float4*)(cbase + 384 + ro);
                float bg;
                bg = readlane_f(Bown, 8*k+0); s0 += a.x*bg; s1 += e.x*bg; s2 += f.x*bg; s3 += h.x*bg;
                bg = readlane_f(Bown, 8*k+2); s0 += a.y*bg; s1 += e.y*bg; s2 += f.y*bg; s3 += h.y*bg;
                bg = readlane_f(Bown, 8*k+4); s0 += a.z*bg; s1 += e.z*bg; s2 += f.z*bg; s3 += h.z*bg;
                bg = readlane_f(Bown, 8*k+6); s0 += a.w*bg; s1 += e.w*bg; s2 += f.w*bg; s3 += h.w*bg;
            }
        } else if (valid) {
            #pragma unroll
            for (int k = 0; k < 8; ++k) {
                const float4 a = gs[sp_idx(tau, 0, k)];
                const float4 e = gs[sp_idx(tau, 1, k)];
                const float4 f = gs[sp_idx(tau, 2, k)];
                const float4 h = gs[sp_idx(tau, 3, k)];
                float bg;
                bg = readlane_f(Bown, 8*k+0); s0 += a.x*bg; s1 += e.x*bg; s2 += f.x*bg; s3 += h.x*bg;
                bg = readlane_f(Bown, 8*k+2); s0 += a.y*bg; s1 += e.y*bg; s2 += f.y*bg; s3 += h.y*bg;
                bg = readlane_f(Bown, 8*k+4); s0 += a.z*bg; s1 += e.z*bg; s2 += f.z*bg; s3 += h.z*bg;
                bg = readlane_f(Bown, 8*k+6); s0 += a.w*bg; s1 += e.w*bg; s2 += f.w*bg; s3 += h.w*bg;
            }
        }
        Ac[0] *= clampf(Cc[0] / fmaxf(Ac[0] * s0, 1e-12f), 0.75f, 1.25f);
        Ac[1] *= clampf(Cc[1] / fmaxf(Ac[1] * s1, 1e-12f), 0.75f, 1.25f);
        Ac[2] *= clampf(Cc[2] / fmaxf(Ac[2] * s2, 1e-12f), 0.75f, 1.25f);
        Ac[3] *= clampf(Cc[3] / fmaxf(Ac[3] * s3, 1e-12f), 0.75f, 1.25f);

        asm volatile("" ::: "memory");   // keep passes separate (no fused 64-reg live set)

        float v[NG];
        if (lcls) {
            #pragma unroll
            for (int k = 0; k < 8; ++k) {
                const int ro = 16 * ((k + rot) & 7);
                const float4 a = *(const float4*)(cbase + ro);
                const float4 e = *(const float4*)(cbase + 128 + ro);
                const float4 f = *(const float4*)(cbase + 256 + ro);
                const float4 h = *(const float4*)(cbase + 384 + ro);
                v[4*k+0] = a.x*Ac[0] + e.x*Ac[1] + f.x*Ac[2] + h.x*Ac[3];
                v[4*k+1] = a.y*Ac[0] + e.y*Ac[1] + f.y*Ac[2] + h.y*Ac[3];
                v[4*k+2] = a.z*Ac[0] + e.z*Ac[1] + f.z*Ac[2] + h.z*Ac[3];
                v[4*k+3] = a.w*Ac[0] + e.w*Ac[1] + f.w*Ac[2] + h.w*Ac[3];
            }
        } else if (valid) {
            #pragma unroll
            for (int k = 0; k < 8; ++k) {
                const float4 a = gs[sp_idx(tau, 0, k)];
                const float4 e = gs[sp_idx(tau, 1, k)];
                const float4 f = gs[sp_idx(tau, 2, k)];
                const float4 h = gs[sp_idx(tau, 3, k)];
                v[4*k+0] = a.x*Ac[0] + e.x*Ac[1] + f.x*Ac[2] + h.x*Ac[3];
                v[4*k+1] = a.y*Ac[0] + e.y*Ac[1] + f.y*Ac[2] + h.y*Ac[3];
                v[4*k+2] = a.z*Ac[0] + e.z*Ac[1] + f.z*Ac[2] + h.z*Ac[3];
                v[4*k+3] = a.w*Ac[0] + e.w*Ac[1] + f.w*Ac[2] + h.w*Ac[3];
            }
        } else {
            #pragma unroll
            for (int g = 0; g < NG; ++g) v[g] = 0.f;
        }
        const float tot = wave_sum32(v, lane);
        const int buf = (q & 1) * (8 * NG);
        if (!(lane & 1)) wred[buf + w * NG + g_own] = tot;
        __syncthreads();
        float s = 0.f;
        #pragma unroll
        for (int w2 = 0; w2 < 8; ++w2) s += wred[buf + w2 * NG + g_own];
        Bown *= clampf(Rown / fmaxf(Bown * s, 1e-12f), 0.75f, 1.25f);
    }

    // park A finals in out's g=0 row (exact positions this thread's k_epi
    // counterpart reads then overwrites) and B finals replicated per quarter
    // in the g=1 row (read at k_epi block start, overwritten after barrier).
    if (valid) {
        float* ap = out + 1 + (size_t)(b * NG) * ND + c0;
        ap[0] = Ac[0]; ap[1] = Ac[1]; ap[2] = Ac[2]; ap[3] = Ac[3];
    }
    if (w == 0 && !(lane & 1)) {
        #pragma unroll
        for (int qq = 0; qq < 4; ++qq)
            out[1 + (size_t)(b * NG + 1) * ND + qq * 500 + g_own] = Bown;
    }
}

// ---- loss-partials path: 512-thr, r0-verbatim (one (b,cx) pair) ----------
__device__ __forceinline__ void loss_path(
        const float* __restrict__ x, const float* __restrict__ nl,
        const float* __restrict__ tgt, const float* __restrict__ W,
        const float* __restrict__ bias, float* __restrict__ res2,
        float* smem, int cx, int b, int t) {
    float* xsl = smem;                 // 256
    float* nsl = smem + 256;           // 256
    float* tgl = smem + 512;           // 252
    float* pt  = smem + 764;           // 16 x 252

    if (t < 256) {
        const float* xb = x + (size_t)b * NG * NDIN;
        float s = 0.f;
        for (int g = 0; g < NG; ++g) s += xb[g * NDIN + t];
        xsl[t] = s;
        const float* nb = nl + (size_t)b * NG * (NM * NE);
        float s2 = 0.f;
        for (int g = 0; g < NG; ++g) s2 += nb[g * (NM * NE) + t];
        nsl[t] = s2;
    }

    int tm = 0, tn = 0;
    if (t >= 16 && t < 152) {
        int p = t - 16;
        for (int m = 0; m < NM; ++m) {
            int c = NM - m;
            if (p < c) { tm = m; tn = m + p; break; }
            p -= c;
        }
    }
    __syncthreads();

    const int d = cx * 250 + t;
    if (t < 250) {
        tgl[t] = tgt[b * ND + d];
        float xw = 0.f;
        #pragma unroll 8
        for (int k = 0; k < NDIN; ++k) xw += xsl[k] * W[(size_t)k * ND + d];
        float we[NE];
        #pragma unroll
        for (int e = 0; e < NE; ++e) we[e] = W[(size_t)(NDIN + e) * ND + d];
        const float base0 = xw + (float)NG * bias[d];
        #pragma unroll
        for (int m = 0; m < NM; ++m) {
            float pm = base0;
            #pragma unroll
            for (int e = 0; e < NE; ++e) pm += nsl[m * NE + e] * we[e];
            pt[m * 252 + t] = pm;
        }
    }
    if (t < 32) {                      // zero-pad cols 250,251
        pt[(t >> 1) * 252 + 250 + (t & 1)] = 0.f;
        if (t < 2) tgl[250 + t] = 0.f;
    }
    __syncthreads();

    float acc = 0.f;
    if (t < 16) {
        const float4* pa  = (const float4*)&pt[t * 252];
        const float4* tga = (const float4*)&tgl[0];
        for (int i = 0; i < 63; ++i) {
            float4 pv = pa[i], tv = tga[i];
            float e0 = pv.x - tv.x, e1 = pv.y - tv.y, e2 = pv.z - tv.z, e3 = pv.w - tv.w;
            acc += e0 * e0 + e1 * e1 + e2 * e2 + e3 * e3;
        }
    } else if (t < 152) {
        const float4* pa = (const float4*)&pt[tm * 252];
        const float4* pb = (const float4*)&pt[tn * 252];
        for (int i = 0; i < 63; ++i) {
            float4 u = pa[i], v = pb[i];
            acc += u.x * v.x + u.y * v.y + u.z * v.z + u.w * v.w;
        }
    }
    if (t < 152) res2[((size_t)b * 8 + cx) * 152 + t] = acc;
}

extern "C" __global__ __launch_bounds__(512)
void mega(const float* __restrict__ x, const float* __restrict__ nl,
          const float* __restrict__ tgt, const float* __restrict__ W,
          const float* __restrict__ bias, const float* __restrict__ xpT,
          const float* __restrict__ spB, const int* __restrict__ tsum,
          float* __restrict__ out, float* __restrict__ res2) {
    extern __shared__ char smem[];     // 133120 B
    const int bid = blockIdx.x;        // 0..255 (exactly 1 block/CU)
    const int t = threadIdx.x;
    if (bid < NB) {
        ipf_path(xpT, spB, tsum, out, smem, bid, t);
    } else {
        const int l = bid - NB;        // 0..191, grid-stride 512 pairs
        #pragma unroll
        for (int rep = 0; rep < 3; ++rep) {
            const int p = l + rep * 192;
            if (p < 512) {
                __syncthreads();
                loss_path(x, nl, tgt, W, bias, res2, (float*)smem,
                          p & 7, p >> 3, t);
            }
        }
    }
}

// ---------------------------------------------------------------------------
// K_EPI: final scale + exact integerization (r5's proven spill-free LDS-
// scratch code).  Grid 256 x 256thr (b = bid>>2, quarter = bid&3), 2 bl/CU.
// Reads A from out g=0 row / B from out g=1 row replicas (written by mega;
// same-thread read-then-write + block barrier => race-free), y0 from
// xpT/streamP, then overwrites all of out with y_int.
// ---------------------------------------------------------------------------
extern "C" __global__ __launch_bounds__(256)
void k_epi(const float* __restrict__ xpT, const float* __restrict__ spB,
           const int* __restrict__ tsum, float* __restrict__ out) {
    extern __shared__ char smem[];     // 65664 B
    const int bid = blockIdx.x;
    const int b = bid >> 2, qq = bid & 3;
    const int tt = threadIdx.x;
    float* bf  = (float*)smem;                                   // B[32]
    float* epf = (float*)(smem + 128 + (size_t)tt * 256);        // frac[32]
    int*   epy = (int*)(smem + 128 + (size_t)tt * 256 + 128);    // yv[32]

    if (tt < 32)
        bf[tt] = out[1 + (size_t)(b * NG + 1) * ND + qq * 500 + tt];
    __syncthreads();
    if (tt >= 250) return;

    const int d0 = qq * 500 + 2 * tt;
    const float A0 = out[1 + (size_t)(b * NG) * ND + d0];
    const float A1 = out[1 + (size_t)(b * NG) * ND + d0 + 1];
    const int2 ci = *(const int2*)(tsum + (size_t)b * ND + d0);
    const float Cc[2] = {(float)ci.x, (float)ci.y};
    const float Aj[2] = {A0, A1};

    #pragma unroll
    for (int j = 0; j < 2; ++j) {
        const int c = d0 + j;
        // gather this column's 8 float4 chunks (g ascending)
        float4 ch[8];
        if (c < XPT_COLS) {
            const float4* cp = (const float4*)(xpT + ((size_t)b * XPT_COLS + c) * NG);
            #pragma unroll
            for (int k = 0; k < 8; ++k) ch[k] = cp[k];
        } else {
            const float4* gsp = (const float4*)(spB + (size_t)b * SP_STRIDE * 4);
            const int tau2 = (c - XPT_COLS) >> 2, cj = (c - XPT_COLS) & 3;
            #pragma unroll
            for (int k = 0; k < 8; ++k) ch[k] = gsp[sp_idx(tau2, cj, k)];
        }
        // pass 1: z = (y0*A)*B, accumulate s (g ascending, r5 order)
        float s = 0.f;
        #pragma unroll
        for (int k = 0; k < 8; ++k) {
            float z;
            z = ch[k].x * Aj[j] * bf[4*k+0]; s += z; epf[(4*k+0+tt)&31] = z;
            z = ch[k].y * Aj[j] * bf[4*k+1]; s += z; epf[(4*k+1+tt)&31] = z;
            z = ch[k].z * Aj[j] * bf[4*k+2]; s += z; epf[(4*k+2+tt)&31] = z;
            z = ch[k].w * Aj[j] * bf[4*k+3]; s += z; epf[(4*k+3+tt)&31] = z;
        }
        const float F = Cc[j] / fmaxf(s, 1e-12f);
        int isum = 0;
        #pragma unroll
        for (int g = 0; g < NG; ++g) {
            const float y = epf[(g+tt)&31] * F;
            const float fl = floorf(y);
            const int yi = (int)fl;
            epf[(g+tt)&31] = y - fl;
            epy[(g+tt)&31] = yi;
            isum += yi;
        }
        const int Ci = (int)Cc[j];
        const int need = Ci - isum;
        const int pos = max(need, 0);
        const int qv = pos >> 5;
        const int rr = pos & 31;
        if (qv > 0) {
            #pragma unroll
            for (int g = 0; g < NG; ++g) epy[(g+tt)&31] += qv;
        }
        #pragma unroll
        for (int g = 0; g < NG; ++g) {       // stable DESCENDING rank on frac
            const float fg = epf[(g+tt)&31];
            int rank = 0;
            #pragma unroll
            for (int h = 0; h < NG; ++h) {
                if (h == g) continue;
                const float fh = epf[(h+tt)&31];
                rank += (h < g) ? (fh >= fg ? 1 : 0) : (fh > fg ? 1 : 0);
            }
            if (rank < rr) epy[(g+tt)&31] += 1;
        }
        // negative residual: one-shot ascending rank among yv>0 (== reference)
        int neg = max(-need, 0);
        neg = min(neg, isum);
        if (__builtin_expect(neg > 0, 0)) {
            const int q2 = neg >> 5;
            int removed = 0;
            #pragma unroll
            for (int g = 0; g < NG; ++g) {
                const int yb = epy[(g+tt)&31];
                const int yn = max(yb - q2, 0);
                removed += yb - yn;
                epy[(g+tt)&31] = yn;
            }
            const int r2 = neg - removed;
            if (r2 > 0) {
                const float INF = __builtin_inff();
                #pragma unroll
                for (int g = 0; g < NG; ++g) {
                    const float fg = (epy[(g+tt)&31] > 0) ? epf[(g+tt)&31] : INF;
                    int rank = 0;
                    #pragma unroll
                    for (int h = 0; h < NG; ++h) {
                        if (h == g) continue;
                        const float fh = (epy[(h+tt)&31] > 0) ? epf[(h+tt)&31] : INF;
                        rank += (h < g) ? (fh <= fg ? 1 : 0) : (fh < fg ? 1 : 0);
                    }
                    if (rank < r2) {
                        const int yb = epy[(g+tt)&31];
                        epy[(g+tt)&31] = max(yb - 1, 0);
                    }
                }
            }
        }
        #pragma unroll
        for (int g = 0; g < NG; ++g)
            out[1 + (size_t)(b * NG + g) * ND + d0 + j] = (float)epy[(g+tt)&31];
    }
}

// K2b: combine the 8 d-chunk partials per b and accumulate the loss.
extern "C" __global__ __launch_bounds__(64)
void k2b_combine(const float* __restrict__ res2, float* __restrict__ out) {
    const int b = blockIdx.x, t = threadIdx.x;
    __shared__ float res[152];
    for (int tau = t; tau < 152; tau += 64) {
        float s = 0.f;
        #pragma unroll
        for (int c = 0; c < 8; ++c) s += res2[((size_t)b * 8 + c) * 152 + tau];
        res[tau] = s;
    }
    __syncthreads();
    if (t == 0) {
        float conf = 0.f;
        for (int m = 0; m < NM; ++m) conf += sqrtf(res[m]);
        conf *= (1.f / NM);
        float pd = 0.f;
        for (int m = 0; m < NM; ++m) {
            const int offm = 16 + m * NM - m * (m - 1) / 2;
            const float sqm = res[offm];
            for (int n = m + 1; n < NM; ++n) {
                const int offn = 16 + n * NM - n * (n - 1) / 2;
                const float sqn = res[offn];
                const float inn = res[offm + (n - m)];
                pd += sqrtf(fmaxf(sqm + sqn - 2.f * inn, 1e-6f));
            }
        }
        pd = 2.f * pd / (float)(NM * (NM - 1));
        atomicAdd(out, (conf - 0.5f * pd) * (1.f / NB));
    }
}

// ---------------------------------------------------------------------------
// K3: x_pred = softplus(concat(x, noise_sample) @ W + bias); cols < 1024 go
// to xpT [b][c][g], cols >= 1024 go DIRECTLY to the lane-interleaved streamP
// layout (so mega's stream loads are coalesced - fixes r4's 4x over-fetch).
// ---------------------------------------------------------------------------
extern "C" __global__ __launch_bounds__(256)
void k3_xpred(const float* __restrict__ x, const float* __restrict__ nsamp,
              const float* __restrict__ W, const float* __restrict__ bias,
              float* __restrict__ xpT, float* __restrict__ spB) {
    const int dx = blockIdx.x;     // 0..1
    const int rb = blockIdx.y;     // 0..255
    const int t  = threadIdx.x;
    __shared__ float xr[8][NK];
    #pragma unroll
    for (int r = 0; r < 8; ++r) {
        const int row = rb * 8 + r;
        xr[r][t] = x[(size_t)row * NDIN + t];
        if (t < NE) xr[r][NDIN + t] = nsamp[row * NE + t];
    }
    __syncthreads();
    if (t >= 250) return;
    const int d = dx * 1000 + 4 * t;
    float acc[8][4];
    #pragma unroll
    for (int r = 0; r < 8; ++r) {
        acc[r][0] = 0.f; acc[r][1] = 0.f; acc[r][2] = 0.f; acc[r][3] = 0.f;
    }
    for (int k = 0; k < NK; k += 4) {
        float4 w[4];
        #pragma unroll
        for (int kk = 0; kk < 4; ++kk) w[kk] = *(const float4*)&W[(size_t)(k + kk) * ND + d];
        #pragma unroll
        for (int r = 0; r < 8; ++r) {
            const float4 xv = *(const float4*)&xr[r][k];
            acc[r][0] += xv.x * w[0].x + xv.y * w[1].x + xv.z * w[2].x + xv.w * w[3].x;
            acc[r][1] += xv.x * w[0].y + xv.y * w[1].y + xv.z * w[2].y + xv.w * w[3].y;
            acc[r][2] += xv.x * w[0].z + xv.y * w[1].z + xv.z * w[2].z + xv.w * w[3].z;
            acc[r][3] += xv.x * w[0].w + xv.y * w[1].w + xv.z * w[2].w + xv.w * w[3].w;
        }
    }
    const float4 bv = *(const float4*)&bias[d];
    const float bvv[4] = {bv.x, bv.y, bv.z, bv.w};
    const int b2 = rb >> 2;            // b = row/32
    const int g0 = (rb & 3) * 8;       // this block's 8-g slice
    #pragma unroll
    for (int dd = 0; dd < 4; ++dd) {
        const int dc = d + dd;
        float4 lo, hi;
        lo.x = softplusf(acc[0][dd] + bvv[dd]);
        lo.y = softplusf(acc[1][dd] + bvv[dd]);
        lo.z = softplusf(acc[2][dd] + bvv[dd]);
        lo.w = softplusf(acc[3][dd] + bvv[dd]);
        hi.x = softplusf(acc[4][dd] + bvv[dd]);
        hi.y = softplusf(acc[5][dd] + bvv[dd]);
        hi.z = softplusf(acc[6][dd] + bvv[dd]);
        hi.w = softplusf(acc[7][dd] + bvv[dd]);
        if (dc < XPT_COLS) {
            float* op = xpT + ((size_t)b2 * XPT_COLS + dc) * NG + g0;
            *(float4*)op       = lo;
            *(float4*)(op + 4) = hi;
        } else {
            float4* sp = (float4*)spB + (size_t)b2 * SP_STRIDE;
            const int tau2 = (dc - XPT_COLS) >> 2, cj = (dc - XPT_COLS) & 3;
            const int kk = g0 >> 2;
            sp[sp_idx(tau2, cj, kk)]     = lo;
            sp[sp_idx(tau2, cj, kk + 1)] = hi;
        }
    }
}

// ---------------------------------------------------------------------------
extern "C" void kernel_launch(void* const* d_in, const int* in_sizes, int n_in,
                              void* d_out, int out_size, void* d_ws, size_t ws_size,
                              hipStream_t stream) {
    const float* x     = (const float*)d_in[0];
    const float* tgt   = (const float*)d_in[1];
    const int*   tsum  = (const int*)d_in[2];
    const float* W     = (const float*)d_in[3];
    const float* bias  = (const float*)d_in[4];
    const float* nl    = (const float*)d_in[5];
    const float* nsamp = (const float*)d_in[6];
    float* out = (float*)d_out;

    (void)in_sizes; (void)n_in; (void)out_size; (void)ws_size;

    // ws layout (total 16,695,296 B == proven round-0..5 footprint):
    //   xpT:     64 * 1024 cols * 32 g * 4 B      =  8,388,608
    //   streamP: 64 * 7808 float4 * 16 B          =  7,995,392
    //   res2:    64 * 8 * 152 * 4 B               =    311,296
    float* xpT  = (float*)d_ws;
    float* spB  = (float*)((char*)d_ws + 8388608);
    float* res2 = (float*)((char*)d_ws + 16384000);

    static int s_attr_done = 0;
    if (!s_attr_done) {
        hipFuncSetAttribute(reinterpret_cast<const void*>(mega),
                            hipFuncAttributeMaxDynamicSharedMemorySize,
                            SMEM_MEGA);
        hipFuncSetAttribute(reinterpret_cast<const void*>(k_epi),
                            hipFuncAttributeMaxDynamicSharedMemorySize,
                            SMEM_EPI);
        s_attr_done = 1;
    }

    hipMemsetAsync(d_out, 0, sizeof(float), stream);   // loss accumulator

    hipLaunchKernelGGL(k3_xpred, dim3(2, 256), dim3(256), 0, stream,
                       x, nsamp, W, bias, xpT, spB);
    hipLaunchKernelGGL(mega, dim3(256), dim3(512), SMEM_MEGA, stream,
                       x, nl, tgt, W, bias, xpT, spB, tsum, out, res2);
    hipLaunchKernelGGL(k_epi, dim3(256), dim3(256), SMEM_EPI, stream,
                       xpT, spB, tsum, out);
    hipLaunchKernelGGL(k2b_combine, dim3(NB), dim3(64), 0, stream, res2, out);
}